// Round 1
// baseline (124515.869 us; speedup 1.0000x reference)
//
#include <hip/hip_runtime.h>
#include <math.h>

#define T_STEPS 512
#define IN_DIM  17
#define HID     512
#define LAT     256
#define BT      16      // batch elements per block
#define NTH     512     // threads per block

// ---- workspace layout (floats) ----
// enc_w1T : [17][256]    (enc_w1 transposed)
// enc_w2T : [256][256]   (enc_w2 transposed)
// w_ihP   : [257][512][4]  packed: {r,z,n,0} rows of w_ih, transposed
// w_hhP   : [512][512][4]  packed: {r,z,n,0} rows of w_hh, transposed
#define OFF_W1T 0
#define OFF_W2T (OFF_W1T + IN_DIM * LAT)
#define OFF_IHP (OFF_W2T + LAT * LAT)
#define OFF_HHP (OFF_IHP + 257 * 512 * 4)
#define WS_FLOATS (OFF_HHP + 512 * 512 * 4)   // 1,644,800 floats = 6.28 MB

__global__ void pack_weights_kernel(const float* __restrict__ enc_w1,
                                    const float* __restrict__ enc_w2,
                                    const float* __restrict__ w_ih,
                                    const float* __restrict__ w_hh,
                                    float* __restrict__ ws) {
    int i = blockIdx.x * 256 + threadIdx.x;   // grid covers 512*512
    if (i < IN_DIM * LAT) {
        int k = i / LAT, j = i % LAT;
        ws[OFF_W1T + i] = enc_w1[(size_t)j * IN_DIM + k];
    }
    if (i < LAT * LAT) {
        int k = i / LAT, j = i % LAT;
        ws[OFF_W2T + i] = enc_w2[(size_t)j * LAT + k];
    }
    if (i < 257 * 512) {
        int k = i / 512, j = i % 512;
        float* o = ws + OFF_IHP + (size_t)i * 4;
        o[0] = w_ih[(size_t)(0   + j) * 257 + k];
        o[1] = w_ih[(size_t)(512 + j) * 257 + k];
        o[2] = w_ih[(size_t)(1024 + j) * 257 + k];
        o[3] = 0.0f;
    }
    if (i < 512 * 512) {
        int k = i / 512, j = i % 512;
        float* o = ws + OFF_HHP + (size_t)i * 4;
        o[0] = w_hh[(size_t)(0   + j) * 512 + k];
        o[1] = w_hh[(size_t)(512 + j) * 512 + k];
        o[2] = w_hh[(size_t)(1024 + j) * 512 + k];
        o[3] = 0.0f;
    }
}

__global__ __launch_bounds__(NTH, 2)
void imu_persist_kernel(const float* __restrict__ x,
                        const float* __restrict__ h0,
                        const float* __restrict__ enc_b1,
                        const float* __restrict__ enc_b2,
                        const float* __restrict__ b_ih,
                        const float* __restrict__ b_hh,
                        const float* __restrict__ q_w, const float* __restrict__ q_b,
                        const float* __restrict__ v_w, const float* __restrict__ v_b,
                        const float* __restrict__ c_w, const float* __restrict__ c_b,
                        const float* __restrict__ ws,
                        float* __restrict__ out)
{
    // transposed activation tiles: [feature][batch]
    __shared__ __align__(16) float hT[HID][BT];      // 32 KB   current hidden state
    __shared__ __align__(16) float ginT[LAT][BT];    // 16 KB   lat (gin[0:256])
    __shared__ __align__(16) float z1h[LAT][8];      // 8 KB    z1 for one batch-half
    __shared__ __align__(16) float xT[IN_DIM][BT];   // 1.06 KB
    __shared__ __align__(16) float sdot[BT][10];     // 640 B
    __shared__ float lds_pad[6000];                  // 24 KB: force 1 block/CU (>80KB)

    const int t  = threadIdx.x;
    const int b0 = blockIdx.x * BT;
    if (t > 100000) lds_pad[0] = 0.f;   // keep pad alive; never executes

    const float*  w1T = ws + OFF_W1T;
    const float*  w2T = ws + OFF_W2T;
    const float4* ihP = (const float4*)(ws + OFF_IHP);
    const float4* hhP = (const float4*)(ws + OFF_HHP);

    // load h0 tile (transposed)
    for (int idx = t; idx < HID * BT; idx += NTH) {
        int b = idx & (BT - 1);
        int k = idx >> 4;
        hT[k][b] = h0[(size_t)(b0 + b) * HID + k];
    }
    float dp0 = 0.f, dp1 = 0.f, dp2 = 0.f;   // meaningful only for t < BT
    __syncthreads();

    for (int step = 0; step < T_STEPS; ++step) {
        // ---- load x_t tile ----
        if (t < IN_DIM * BT) {
            int b = t / IN_DIM, k = t % IN_DIM;
            xT[k][b] = x[((size_t)(b0 + b) * T_STEPS + step) * IN_DIM + k];
        }
        __syncthreads();

        // ---- encoder, two batch halves (keeps z1 buffer at 256x8) ----
        #pragma unroll
        for (int half = 0; half < 2; ++half) {
            {   // E1: z1 = relu(x @ w1T + b1)
                int j  = t & (LAT - 1);
                int i4 = (t >> 8) * 4;
                float a0 = 0.f, a1 = 0.f, a2 = 0.f, a3 = 0.f;
                #pragma unroll
                for (int k = 0; k < IN_DIM; ++k) {
                    float w = w1T[k * LAT + j];
                    a0 += w * xT[k][half * 8 + i4 + 0];
                    a1 += w * xT[k][half * 8 + i4 + 1];
                    a2 += w * xT[k][half * 8 + i4 + 2];
                    a3 += w * xT[k][half * 8 + i4 + 3];
                }
                float bb = enc_b1[j];
                z1h[j][i4 + 0] = fmaxf(a0 + bb, 0.f);
                z1h[j][i4 + 1] = fmaxf(a1 + bb, 0.f);
                z1h[j][i4 + 2] = fmaxf(a2 + bb, 0.f);
                z1h[j][i4 + 3] = fmaxf(a3 + bb, 0.f);
            }
            __syncthreads();
            {   // E2: lat = relu(z1 @ w2T + b2) -> ginT
                int j  = t & (LAT - 1);
                int i4 = (t >> 8) * 4;
                float a0 = 0.f, a1 = 0.f, a2 = 0.f, a3 = 0.f;
                for (int k = 0; k < LAT; ++k) {
                    float w = w2T[k * LAT + j];
                    float4 zv = *(const float4*)&z1h[k][i4];
                    a0 += w * zv.x; a1 += w * zv.y; a2 += w * zv.z; a3 += w * zv.w;
                }
                float bb = enc_b2[j];
                ginT[j][half * 8 + i4 + 0] = fmaxf(a0 + bb, 0.f);
                ginT[j][half * 8 + i4 + 1] = fmaxf(a1 + bb, 0.f);
                ginT[j][half * 8 + i4 + 2] = fmaxf(a2 + bb, 0.f);
                ginT[j][half * 8 + i4 + 3] = fmaxf(a3 + bb, 0.f);
            }
            __syncthreads();
        }

        // ---- GRU gates: thread t owns gate-triple j = t, all 16 batch elems ----
        {
            const int j = t;
            float bias_r  = b_ih[j] + b_hh[j];
            float bias_z  = b_ih[512 + j] + b_hh[512 + j];
            float bias_in = b_ih[1024 + j];
            float bias_hn = b_hh[1024 + j];
            float ar[BT], az[BT], ain[BT], ahn[BT];
            #pragma unroll
            for (int b2 = 0; b2 < BT; ++b2) {
                ar[b2] = bias_r; az[b2] = bias_z; ain[b2] = bias_in; ahn[b2] = bias_hn;
            }

#define GATE_FMA4(q, gv, third)                                              \
            ar[4*q+0] += w.x*gv.x; az[4*q+0] += w.y*gv.x; third[4*q+0] += w.z*gv.x; \
            ar[4*q+1] += w.x*gv.y; az[4*q+1] += w.y*gv.y; third[4*q+1] += w.z*gv.y; \
            ar[4*q+2] += w.x*gv.z; az[4*q+2] += w.y*gv.z; third[4*q+2] += w.z*gv.z; \
            ar[4*q+3] += w.x*gv.w; az[4*q+3] += w.y*gv.w; third[4*q+3] += w.z*gv.w;

            // gi part: k over lat (0..255)
            for (int k = 0; k < LAT; ++k) {
                float4 w = ihP[(size_t)k * 512 + j];
                const float4* g4 = (const float4*)ginT[k];
                #pragma unroll
                for (int q = 0; q < 4; ++q) { float4 gv = g4[q]; GATE_FMA4(q, gv, ain) }
            }
            // gi part: k = 256 is dt
            {
                float4 w = ihP[(size_t)LAT * 512 + j];
                #pragma unroll
                for (int b2 = 0; b2 < BT; ++b2) {
                    float dtv = xT[IN_DIM - 1][b2];
                    ar[b2] += w.x * dtv; az[b2] += w.y * dtv; ain[b2] += w.z * dtv;
                }
            }
            // gh part: k over hid (0..511)
            for (int k = 0; k < HID; ++k) {
                float4 w = hhP[(size_t)k * 512 + j];
                const float4* g4 = (const float4*)hT[k];
                #pragma unroll
                for (int q = 0; q < 4; ++q) { float4 gv = g4[q]; GATE_FMA4(q, gv, ahn) }
            }
#undef GATE_FMA4
            // gate nonlinearity; h_new staged in ar[]
            #pragma unroll
            for (int b2 = 0; b2 < BT; ++b2) {
                float r  = 1.f / (1.f + expf(-ar[b2]));
                float zz = 1.f / (1.f + expf(-az[b2]));
                float n  = tanhf(ain[b2] + r * ahn[b2]);
                float ho = hT[j][b2];
                ar[b2] = (1.f - zz) * n + zz * ho;
            }
            __syncthreads();             // everyone done READING old h
            #pragma unroll
            for (int b2 = 0; b2 < BT; ++b2) hT[j][b2] = ar[b2];
        }
        __syncthreads();                 // h_new visible

        // ---- heads: 10 dots of K=512 per batch elem ----
        if (t < BT * 10) {
            int b = t & 15, d = t >> 4;
            const float* wr = (d < 4) ? (q_w + (size_t)d * HID)
                             : (d < 7) ? (v_w + (size_t)(d - 4) * HID)
                                       : (c_w + (size_t)(d - 7) * HID);
            float acc = 0.f;
            for (int k = 0; k < HID; ++k) acc += wr[k] * hT[k][b];
            sdot[b][d] = acc;
        }
        __syncthreads();

        // ---- quat / rotation / dp update (one lane per batch elem) ----
        if (t < BT) {
            int b = t;
            float q0 = sdot[b][0] + q_b[0], q1 = sdot[b][1] + q_b[1];
            float q2 = sdot[b][2] + q_b[2], q3 = sdot[b][3] + q_b[3];
            float nrm = sqrtf(q0*q0 + q1*q1 + q2*q2 + q3*q3);
            nrm = fmaxf(nrm, 1e-12f);
            float qw = q0/nrm, qx = q1/nrm, qy = q2/nrm, qz = q3/nrm;
            float vx = sdot[b][4] + v_b[0], vy = sdot[b][5] + v_b[1], vz = sdot[b][6] + v_b[2];
            float ex = sdot[b][7] + c_b[0], ey = sdot[b][8] + c_b[1], ez = sdot[b][9] + c_b[2];
            float dtv = xT[IN_DIM - 1][b];
            float a0 = xT[0][b], a1 = xT[1][b], a2 = xT[2][b];
            float xx = qx*qx, yy = qy*qy, zz = qz*qz;
            float xy = qx*qy, xz = qx*qz, yz = qy*qz;
            float wx = qw*qx, wy = qw*qy, wz = qw*qz;
            float aw0 = (1.f - 2.f*(yy+zz))*a0 + 2.f*(xy-wz)*a1 + 2.f*(xz+wy)*a2;
            float aw1 = 2.f*(xy+wz)*a0 + (1.f - 2.f*(xx+zz))*a1 + 2.f*(yz-wx)*a2;
            float aw2 = 2.f*(xz-wy)*a0 + 2.f*(yz+wx)*a1 + (1.f - 2.f*(xx+yy))*a2;
            float hdt2 = 0.5f * dtv * dtv;
            dp0 += vx*dtv + aw0*hdt2 + ex;
            dp1 += vy*dtv + aw1*hdt2 + ey;
            dp2 += vz*dtv + aw2*hdt2 + ez;
        }
        __syncthreads();   // protect xT/sdot before next step
    }

    if (t < BT) {
        out[(size_t)(b0 + t) * 3 + 0] = dp0;
        out[(size_t)(b0 + t) * 3 + 1] = dp1;
        out[(size_t)(b0 + t) * 3 + 2] = dp2;
    }
}

extern "C" void kernel_launch(void* const* d_in, const int* in_sizes, int n_in,
                              void* d_out, int out_size, void* d_ws, size_t ws_size,
                              hipStream_t stream) {
    const float* x      = (const float*)d_in[0];
    const float* h0     = (const float*)d_in[1];
    const float* enc_w1 = (const float*)d_in[2];
    const float* enc_b1 = (const float*)d_in[3];
    const float* enc_w2 = (const float*)d_in[4];
    const float* enc_b2 = (const float*)d_in[5];
    const float* w_ih   = (const float*)d_in[6];
    const float* w_hh   = (const float*)d_in[7];
    const float* b_ih   = (const float*)d_in[8];
    const float* b_hh   = (const float*)d_in[9];
    const float* q_w    = (const float*)d_in[10];
    const float* q_b    = (const float*)d_in[11];
    const float* v_w    = (const float*)d_in[12];
    const float* v_b    = (const float*)d_in[13];
    const float* c_w    = (const float*)d_in[14];
    const float* c_b    = (const float*)d_in[15];
    float* ws  = (float*)d_ws;
    float* out = (float*)d_out;

    hipLaunchKernelGGL(pack_weights_kernel, dim3(1024), dim3(256), 0, stream,
                       enc_w1, enc_w2, w_ih, w_hh, ws);
    hipLaunchKernelGGL(imu_persist_kernel, dim3(4096 / BT), dim3(NTH), 0, stream,
                       x, h0, enc_b1, enc_b2, b_ih, b_hh,
                       q_w, q_b, v_w, v_b, c_w, c_b, ws, out);
}

// Round 2
// 28849.911 us; speedup vs baseline: 4.3160x; 4.3160x over previous
//
#include <hip/hip_runtime.h>
#include <math.h>

#define T_STEPS 512
#define IN_DIM  17
#define HID     512
#define LAT     256
#define BT      16
#define NTH     512

typedef __attribute__((ext_vector_type(8))) _Float16 half8;
typedef __attribute__((ext_vector_type(4))) float    f32x4;

// ---------------- workspace layout (byte offsets, all 16B-aligned) ----------
// w2P  : E2 B-frags  [16 nt][8 kt][64 lane][8 j] fp16         131072 B
// wihP : GI B-frags  [96 nt][8 kt][64 lane][8 j] fp16         786432 B
// whhP : GH B-frags  [96 nt][16 kt][64 lane][8 j] fp16       1572864 B
// w1P  : E1 B-frags  [16 nt][64 lane][8 j] fp16 (k>=17 -> 0)   16384 B
// w256 : w_ih[:,256] fp32 [1536]                                6144 B
// bcomb: fp32 [1536]  g<1024: b_ih+b_hh ; g>=1024: b_ih         6144 B
// bhn  : fp32 [512]   b_hh[1024+j]                              2048 B
#define OFF_W2P   0
#define OFF_WIHP  131072
#define OFF_WHHP  917504
#define OFF_W1P   2490368
#define OFF_W256  2506752
#define OFF_BCOMB 2512896
#define OFF_BHN   2519040

static __device__ inline unsigned short f2h(float f) {
    union { _Float16 h; unsigned short u; } cv;
    cv.h = (_Float16)f;
    return cv.u;
}

__global__ void pack_kernel(const float* __restrict__ enc_w1,
                            const float* __restrict__ enc_w2,
                            const float* __restrict__ w_ih,
                            const float* __restrict__ w_hh,
                            const float* __restrict__ b_ih,
                            const float* __restrict__ b_hh,
                            unsigned char* __restrict__ ws) {
    unsigned short* w2P  = (unsigned short*)(ws + OFF_W2P);
    unsigned short* wihP = (unsigned short*)(ws + OFF_WIHP);
    unsigned short* whhP = (unsigned short*)(ws + OFF_WHHP);
    unsigned short* w1P  = (unsigned short*)(ws + OFF_W1P);
    float* w256  = (float*)(ws + OFF_W256);
    float* bcomb = (float*)(ws + OFF_BCOMB);
    float* bhn   = (float*)(ws + OFF_BHN);

    const int tid = blockIdx.x * blockDim.x + threadIdx.x;
    const int stride = gridDim.x * blockDim.x;

    for (int idx = tid; idx < 96 * 16 * 64 * 8; idx += stride) {   // whhP
        int j = idx & 7, l = (idx >> 3) & 63, kt = (idx >> 9) & 15, nt = idx >> 13;
        int g = nt * 16 + (l & 15);
        int k = kt * 32 + ((l >> 4) & 3) * 8 + j;
        whhP[idx] = f2h(w_hh[(size_t)g * 512 + k]);
    }
    for (int idx = tid; idx < 96 * 8 * 64 * 8; idx += stride) {    // wihP (k<256)
        int j = idx & 7, l = (idx >> 3) & 63, kt = (idx >> 9) & 7, nt = idx >> 12;
        int g = nt * 16 + (l & 15);
        int k = kt * 32 + ((l >> 4) & 3) * 8 + j;
        wihP[idx] = f2h(w_ih[(size_t)g * 257 + k]);
    }
    for (int idx = tid; idx < 16 * 8 * 64 * 8; idx += stride) {    // w2P
        int j = idx & 7, l = (idx >> 3) & 63, kt = (idx >> 9) & 7, nt = idx >> 12;
        int n = nt * 16 + (l & 15);
        int k = kt * 32 + ((l >> 4) & 3) * 8 + j;
        w2P[idx] = f2h(enc_w2[(size_t)n * 256 + k]);
    }
    for (int idx = tid; idx < 16 * 64 * 8; idx += stride) {        // w1P
        int j = idx & 7, l = (idx >> 3) & 63, nt = idx >> 9;
        int n = nt * 16 + (l & 15);
        int k = ((l >> 4) & 3) * 8 + j;
        w1P[idx] = (k < IN_DIM) ? f2h(enc_w1[(size_t)n * IN_DIM + k]) : (unsigned short)0;
    }
    for (int idx = tid; idx < 1536; idx += stride) {
        w256[idx]  = w_ih[(size_t)idx * 257 + 256];
        bcomb[idx] = (idx < 1024) ? (b_ih[idx] + b_hh[idx]) : b_ih[idx];
    }
    for (int idx = tid; idx < 512; idx += stride) bhn[idx] = b_hh[1024 + idx];
}

__global__ __launch_bounds__(NTH, 2)
void imu_mfma_kernel(const float* __restrict__ x,
                     const float* __restrict__ h0,
                     const float* __restrict__ enc_b1,
                     const float* __restrict__ enc_b2,
                     const float* __restrict__ q_w, const float* __restrict__ q_b,
                     const float* __restrict__ v_w, const float* __restrict__ v_b,
                     const float* __restrict__ c_w, const float* __restrict__ c_b,
                     const unsigned char* __restrict__ ws,
                     float* __restrict__ out)
{
    // A-fragment-layout LDS (rows padded so 16-lane b128 reads are <=2-way)
    __shared__ __align__(16) unsigned short xbf[16][32];     // x tile (k>=17 zero)
    __shared__ __align__(16) float          xf[4][16];       // acc0..2, dt
    __shared__ __align__(16) unsigned short z1bf[16][264];
    __shared__ __align__(16) unsigned short latbf[16][264];
    __shared__ __align__(16) unsigned short hbf[16][520];
    __shared__ __align__(16) float          h32[16][516];
    __shared__ __align__(16) float          sdot[16][10][2];
    __shared__ __align__(16) unsigned short w1L[16 * 64 * 8];
    __shared__ float eb1L[256], eb2L[256], bcombL[1536], bhnL[512], w256L[1536];

    const unsigned short* w2P  = (const unsigned short*)(ws + OFF_W2P);
    const unsigned short* wihP = (const unsigned short*)(ws + OFF_WIHP);
    const unsigned short* whhP = (const unsigned short*)(ws + OFF_WHHP);
    const unsigned short* w1P  = (const unsigned short*)(ws + OFF_W1P);
    const float* w256 = (const float*)(ws + OFF_W256);
    const float* bcm  = (const float*)(ws + OFF_BCOMB);
    const float* bhnw = (const float*)(ws + OFF_BHN);

    const int t   = threadIdx.x;
    const int w   = t >> 6;       // wave 0..7
    const int l   = t & 63;
    const int l15 = l & 15;
    const int lq  = (l >> 4) & 3;
    const int b0  = blockIdx.x * BT;
    const int rot = blockIdx.x;

    // ---- one-time init ----
    for (int idx = t; idx < 240; idx += NTH) { int b = idx / 15, k = 17 + idx % 15; xbf[b][k] = 0; }
    for (int idx = t; idx < 16 * 64 * 8; idx += NTH) w1L[idx] = w1P[idx];
    for (int idx = t; idx < 256; idx += NTH) { eb1L[idx] = enc_b1[idx]; eb2L[idx] = enc_b2[idx]; }
    for (int idx = t; idx < 1536; idx += NTH) { bcombL[idx] = bcm[idx]; w256L[idx] = w256[idx]; }
    for (int idx = t; idx < 512; idx += NTH) bhnL[idx] = bhnw[idx];
    for (int idx = t; idx < 16 * 512; idx += NTH) {
        int b = idx >> 9, k = idx & 511;
        float v = h0[(size_t)(b0 + b) * HID + k];
        h32[b][k] = v; hbf[b][k] = f2h(v);
    }
    float dp0 = 0.f, dp1 = 0.f, dp2 = 0.f;
    __syncthreads();

    for (int step = 0; step < T_STEPS; ++step) {
        // ---- (a) load x tile ----
        if (t < 272) {
            int b = t / 17, k = t % 17;
            float v = x[((size_t)(b0 + b) * T_STEPS + step) * IN_DIM + k];
            xbf[b][k] = f2h(v);
            if (k < 3)   xf[k][b] = v;
            if (k == 16) xf[3][b] = v;
        }
        __syncthreads();

        // ---- E1: z1 = relu(x @ w1T + b1) ----
        {
            f32x4 a0 = {0.f,0.f,0.f,0.f}, a1 = {0.f,0.f,0.f,0.f};
            const int nt0 = 2 * w, nt1 = 2 * w + 1;
            half8 av = *(const half8*)&xbf[l15][lq * 8];
            half8 bv0 = *(const half8*)&w1L[((size_t)nt0 * 64 + l) * 8];
            half8 bv1 = *(const half8*)&w1L[((size_t)nt1 * 64 + l) * 8];
            a0 = __builtin_amdgcn_mfma_f32_16x16x32_f16(av, bv0, a0, 0, 0, 0);
            a1 = __builtin_amdgcn_mfma_f32_16x16x32_f16(av, bv1, a1, 0, 0, 0);
            #pragma unroll
            for (int i = 0; i < 4; ++i) {
                int m = lq * 4 + i;
                int n0 = nt0 * 16 + l15, n1 = nt1 * 16 + l15;
                z1bf[m][n0] = f2h(fmaxf(a0[i] + eb1L[n0], 0.f));
                z1bf[m][n1] = f2h(fmaxf(a1[i] + eb1L[n1], 0.f));
            }
        }
        __syncthreads();

        // ---- E2: lat = relu(z1 @ w2T + b2) ----
        {
            f32x4 a0 = {0.f,0.f,0.f,0.f}, a1 = {0.f,0.f,0.f,0.f};
            const int nt0 = 2 * w, nt1 = 2 * w + 1;
            #pragma unroll
            for (int ktt = 0; ktt < 8; ++ktt) {
                int kt = (ktt + rot) & 7;
                half8 av = *(const half8*)&z1bf[l15][kt * 32 + lq * 8];
                half8 bv0 = *(const half8*)(w2P + ((size_t)(nt0 * 8 + kt) * 64 + l) * 8);
                half8 bv1 = *(const half8*)(w2P + ((size_t)(nt1 * 8 + kt) * 64 + l) * 8);
                a0 = __builtin_amdgcn_mfma_f32_16x16x32_f16(av, bv0, a0, 0, 0, 0);
                a1 = __builtin_amdgcn_mfma_f32_16x16x32_f16(av, bv1, a1, 0, 0, 0);
            }
            #pragma unroll
            for (int i = 0; i < 4; ++i) {
                int m = lq * 4 + i;
                int n0 = nt0 * 16 + l15, n1 = nt1 * 16 + l15;
                latbf[m][n0] = f2h(fmaxf(a0[i] + eb2L[n0], 0.f));
                latbf[m][n1] = f2h(fmaxf(a1[i] + eb2L[n1], 0.f));
            }
        }
        __syncthreads();

        // ---- GI (K=256 over lat) + GH (K=512 over h_old), 12 N-tiles/wave ----
        f32x4 aR[4], aZ[4], aIN[4], aHN[4];
        #pragma unroll
        for (int jt = 0; jt < 4; ++jt) {
            aR[jt] = (f32x4){0.f,0.f,0.f,0.f}; aZ[jt] = (f32x4){0.f,0.f,0.f,0.f};
            aIN[jt] = (f32x4){0.f,0.f,0.f,0.f}; aHN[jt] = (f32x4){0.f,0.f,0.f,0.f};
        }
        for (int ktt = 0; ktt < 8; ++ktt) {
            int kt = (ktt + rot) & 7;
            half8 av = *(const half8*)&latbf[l15][kt * 32 + lq * 8];
            #pragma unroll
            for (int jt = 0; jt < 4; ++jt) {
                half8 br = *(const half8*)(wihP + ((size_t)((w * 4 + jt) * 8 + kt) * 64 + l) * 8);
                half8 bz = *(const half8*)(wihP + ((size_t)((32 + w * 4 + jt) * 8 + kt) * 64 + l) * 8);
                half8 bn = *(const half8*)(wihP + ((size_t)((64 + w * 4 + jt) * 8 + kt) * 64 + l) * 8);
                aR[jt]  = __builtin_amdgcn_mfma_f32_16x16x32_f16(av, br, aR[jt], 0, 0, 0);
                aZ[jt]  = __builtin_amdgcn_mfma_f32_16x16x32_f16(av, bz, aZ[jt], 0, 0, 0);
                aIN[jt] = __builtin_amdgcn_mfma_f32_16x16x32_f16(av, bn, aIN[jt], 0, 0, 0);
            }
        }
        for (int ktt = 0; ktt < 16; ++ktt) {
            int kt = (ktt + rot) & 15;
            half8 av = *(const half8*)&hbf[l15][kt * 32 + lq * 8];
            #pragma unroll
            for (int jt = 0; jt < 4; ++jt) {
                half8 br = *(const half8*)(whhP + ((size_t)((w * 4 + jt) * 16 + kt) * 64 + l) * 8);
                half8 bz = *(const half8*)(whhP + ((size_t)((32 + w * 4 + jt) * 16 + kt) * 64 + l) * 8);
                half8 bn = *(const half8*)(whhP + ((size_t)((64 + w * 4 + jt) * 16 + kt) * 64 + l) * 8);
                aR[jt]  = __builtin_amdgcn_mfma_f32_16x16x32_f16(av, br, aR[jt], 0, 0, 0);
                aZ[jt]  = __builtin_amdgcn_mfma_f32_16x16x32_f16(av, bz, aZ[jt], 0, 0, 0);
                aHN[jt] = __builtin_amdgcn_mfma_f32_16x16x32_f16(av, bn, aHN[jt], 0, 0, 0);
            }
        }
        __syncthreads();   // all waves done reading old hbf/h32 state

        // ---- gate nonlinearity + h update (this wave owns h-dims w*64..w*64+63) ----
        #pragma unroll
        for (int jt = 0; jt < 4; ++jt) {
            int jd = w * 64 + jt * 16 + l15;
            float bR = bcombL[jd], bZ = bcombL[512 + jd];
            float bIN = bcombL[1024 + jd], bHN = bhnL[jd];
            float wr2 = w256L[jd], wz2 = w256L[512 + jd], wn2 = w256L[1024 + jd];
            #pragma unroll
            for (int i = 0; i < 4; ++i) {
                int m = lq * 4 + i;
                float dtv = xf[3][m];
                float gr = aR[jt][i] + bR + dtv * wr2;
                float gz = aZ[jt][i] + bZ + dtv * wz2;
                float gin_ = aIN[jt][i] + bIN + dtv * wn2;
                float ghn_ = aHN[jt][i] + bHN;
                float r = 1.f / (1.f + __expf(-gr));
                float zg = 1.f / (1.f + __expf(-gz));
                float narg = gin_ + r * ghn_;
                float n = 1.f - 2.f / (__expf(2.f * narg) + 1.f);
                float ho = h32[m][jd];
                float hn = (1.f - zg) * n + zg * ho;
                h32[m][jd] = hn;
                hbf[m][jd] = f2h(hn);
            }
        }
        __syncthreads();   // h_new complete

        // ---- heads: 10 dots x 16 batch, K split in halves ----
        if (t < 320) {
            int d = t >> 5, sub = t & 31, b = sub & 15, kh = sub >> 4;
            const float* wr = (d < 4) ? (q_w + (size_t)d * HID)
                             : (d < 7) ? (v_w + (size_t)(d - 4) * HID)
                                       : (c_w + (size_t)(d - 7) * HID);
            const float* hrow = &h32[b][kh * 256];
            const float* wrow = wr + kh * 256;
            float acc = 0.f;
            #pragma unroll 8
            for (int k0 = 0; k0 < 256; k0 += 4) {
                float4 wv = *(const float4*)(wrow + k0);
                float4 hv = *(const float4*)(hrow + k0);
                acc += wv.x * hv.x + wv.y * hv.y + wv.z * hv.z + wv.w * hv.w;
            }
            sdot[b][d][kh] = acc;
        }
        __syncthreads();

        // ---- quat / rotation / dp (one lane per batch elem) ----
        if (t < BT) {
            int b = t;
            float s[10];
            #pragma unroll
            for (int d = 0; d < 10; ++d) s[d] = sdot[b][d][0] + sdot[b][d][1];
            float q0 = s[0] + q_b[0], q1 = s[1] + q_b[1];
            float q2 = s[2] + q_b[2], q3 = s[3] + q_b[3];
            float nrm = sqrtf(q0*q0 + q1*q1 + q2*q2 + q3*q3);
            nrm = fmaxf(nrm, 1e-12f);
            float qw = q0/nrm, qx = q1/nrm, qy = q2/nrm, qz = q3/nrm;
            float vx = s[4] + v_b[0], vy = s[5] + v_b[1], vz = s[6] + v_b[2];
            float ex = s[7] + c_b[0], ey = s[8] + c_b[1], ez = s[9] + c_b[2];
            float dtv = xf[3][b];
            float a0 = xf[0][b], a1 = xf[1][b], a2 = xf[2][b];
            float xx = qx*qx, yy = qy*qy, zz = qz*qz;
            float xy = qx*qy, xz = qx*qz, yz = qy*qz;
            float wxq = qw*qx, wyq = qw*qy, wzq = qw*qz;
            float aw0 = (1.f - 2.f*(yy+zz))*a0 + 2.f*(xy-wzq)*a1 + 2.f*(xz+wyq)*a2;
            float aw1 = 2.f*(xy+wzq)*a0 + (1.f - 2.f*(xx+zz))*a1 + 2.f*(yz-wxq)*a2;
            float aw2 = 2.f*(xz-wyq)*a0 + 2.f*(yz+wxq)*a1 + (1.f - 2.f*(xx+yy))*a2;
            float hdt2 = 0.5f * dtv * dtv;
            dp0 += vx*dtv + aw0*hdt2 + ex;
            dp1 += vy*dtv + aw1*hdt2 + ey;
            dp2 += vz*dtv + aw2*hdt2 + ez;
        }
        __syncthreads();   // protect xbf/xf/sdot before next step
    }

    if (t < BT) {
        out[(size_t)(b0 + t) * 3 + 0] = dp0;
        out[(size_t)(b0 + t) * 3 + 1] = dp1;
        out[(size_t)(b0 + t) * 3 + 2] = dp2;
    }
}

extern "C" void kernel_launch(void* const* d_in, const int* in_sizes, int n_in,
                              void* d_out, int out_size, void* d_ws, size_t ws_size,
                              hipStream_t stream) {
    const float* x      = (const float*)d_in[0];
    const float* h0     = (const float*)d_in[1];
    const float* enc_w1 = (const float*)d_in[2];
    const float* enc_b1 = (const float*)d_in[3];
    const float* enc_w2 = (const float*)d_in[4];
    const float* enc_b2 = (const float*)d_in[5];
    const float* w_ih   = (const float*)d_in[6];
    const float* w_hh   = (const float*)d_in[7];
    const float* b_ih   = (const float*)d_in[8];
    const float* b_hh   = (const float*)d_in[9];
    const float* q_w    = (const float*)d_in[10];
    const float* q_b    = (const float*)d_in[11];
    const float* v_w    = (const float*)d_in[12];
    const float* v_b    = (const float*)d_in[13];
    const float* c_w    = (const float*)d_in[14];
    const float* c_b    = (const float*)d_in[15];
    unsigned char* ws = (unsigned char*)d_ws;
    float* out = (float*)d_out;

    hipLaunchKernelGGL(pack_kernel, dim3(1536), dim3(512), 0, stream,
                       enc_w1, enc_w2, w_ih, w_hh, b_ih, b_hh, ws);
    hipLaunchKernelGGL(imu_mfma_kernel, dim3(4096 / BT), dim3(NTH), 0, stream,
                       x, h0, enc_b1, enc_b2, q_w, q_b, v_w, v_b, c_w, c_b, ws, out);
}